// Round 2
// baseline (232.830 us; speedup 1.0000x reference)
//
#include <hip/hip_runtime.h>
#include <stdint.h>

typedef __attribute__((ext_vector_type(4))) int i32x4;

#define N_FRAMES 16386
#define D_DIM    1024
#define O_DIM    2048
#define L_CTX    3
#define K_DIM    3072   // D_DIM * L_CTX
#define T_DIM    16384  // N_FRAMES - L_CTX + 1
#define NKT      48     // K_DIM / 64

// workspace byte offsets
#define WS_MM     0u        // 2 x uint (flipped min/max)
#define WS_PARAMS 64u       // Params
#define WS_CO     256u      // O_DIM int32
#define WS_S      16384u    // N_FRAMES int32
#define WS_CT     98304u    // T_DIM int32
#define WS_QW     262144u   // O_DIM*K_DIM int8
#define WS_QX     8388608u  // N_FRAMES*D_DIM int8  (ends ~25.2 MB)

struct Params {
  float w_scale, in_scale, cscale;
  int   w_zp, in_zp, konst;
};

typedef __attribute__((address_space(3))) void       lds_void;
typedef const __attribute__((address_space(1))) void gbl_void;

__device__ __forceinline__ unsigned flip_f(float f) {
  unsigned u = __float_as_uint(f);
  return (u & 0x80000000u) ? ~u : (u | 0x80000000u);
}
__device__ __forceinline__ float unflip_f(unsigned v) {
  unsigned u = (v & 0x80000000u) ? (v ^ 0x80000000u) : ~v;
  return __uint_as_float(u);
}

__global__ void init_kernel(unsigned* mm) {
  mm[0] = 0xFFFFFFFFu;  // min accumulator (flipped space)
  mm[1] = 0u;           // max accumulator
}

__global__ __launch_bounds__(256) void wminmax_kernel(const float4* __restrict__ w,
                                                      unsigned* mm, int n4) {
  unsigned lmin = 0xFFFFFFFFu, lmax = 0u;
  for (int i = blockIdx.x * blockDim.x + threadIdx.x; i < n4; i += gridDim.x * blockDim.x) {
    float4 v = w[i];
    unsigned a = flip_f(v.x), b = flip_f(v.y), c = flip_f(v.z), d = flip_f(v.w);
    lmin = min(lmin, min(min(a, b), min(c, d)));
    lmax = max(lmax, max(max(a, b), max(c, d)));
  }
#pragma unroll
  for (int off = 32; off > 0; off >>= 1) {
    lmin = min(lmin, (unsigned)__shfl_xor((int)lmin, off, 64));
    lmax = max(lmax, (unsigned)__shfl_xor((int)lmax, off, 64));
  }
  if ((threadIdx.x & 63) == 0) {
    atomicMin(&mm[0], lmin);
    atomicMax(&mm[1], lmax);
  }
}

__global__ void params_kernel(const unsigned* __restrict__ mm,
                              const float* __restrict__ in_min,
                              const float* __restrict__ in_max,
                              Params* __restrict__ p) {
  float wmin = unflip_f(mm[0]);
  float wmax = unflip_f(mm[1]);
  float ws = (wmax - wmin) / 254.0f;
  float wz = -127.0f - wmin / ws;
  wz = fminf(fmaxf(wz, -127.0f), 127.0f);
  int wzp = (int)wz;  // trunc toward zero, matches jnp.trunc->int
  float imin = *in_min, imax = *in_max;
  float is = (imax - imin) / 254.0f;
  float iz = -127.0f - imin / is;
  iz = fminf(fmaxf(iz, -127.0f), 127.0f);
  int izp = (int)iz;
  p->w_scale = ws; p->in_scale = is; p->cscale = is * ws;
  p->w_zp = wzp;   p->in_zp = izp;
  p->konst = K_DIM * wzp * izp;
}

// one block per output row o: quantize weight row, write dequant, rowsum -> co
__global__ __launch_bounds__(256) void quantw_kernel(
    const float* __restrict__ w, const float* __restrict__ bias,
    const Params* __restrict__ p, int8_t* __restrict__ qw,
    int* __restrict__ co, float* __restrict__ dq, float* __restrict__ bias_out) {
  const int o = blockIdx.x;
  const float ws = p->w_scale;
  const float zpf = (float)p->w_zp;
  const float* wrow = w + (size_t)o * K_DIM;
  float* dqrow = dq + (size_t)o * K_DIM;
  int8_t* qrow = qw + (size_t)o * K_DIM;
  int sum = 0;
#pragma unroll
  for (int pass = 0; pass < 3; ++pass) {
    const int k = (pass << 10) + (threadIdx.x << 2);
    float4 v = *(const float4*)(wrow + k);
    int8_t c0 = (int8_t)(int)rintf(v.x / ws + zpf);
    int8_t c1 = (int8_t)(int)rintf(v.y / ws + zpf);
    int8_t c2 = (int8_t)(int)rintf(v.z / ws + zpf);
    int8_t c3 = (int8_t)(int)rintf(v.w / ws + zpf);
    sum += (int)c0 + (int)c1 + (int)c2 + (int)c3;
    unsigned packed = (unsigned)(uint8_t)c0 | ((unsigned)(uint8_t)c1 << 8)
                    | ((unsigned)(uint8_t)c2 << 16) | ((unsigned)(uint8_t)c3 << 24);
    *(unsigned*)(qrow + k) = packed;
    float4 d;
    d.x = ((float)c0 - zpf) * ws;
    d.y = ((float)c1 - zpf) * ws;
    d.z = ((float)c2 - zpf) * ws;
    d.w = ((float)c3 - zpf) * ws;
    *(float4*)(dqrow + k) = d;
  }
  __shared__ int red[4];
#pragma unroll
  for (int off = 32; off > 0; off >>= 1) sum += __shfl_xor(sum, off, 64);
  if ((threadIdx.x & 63) == 0) red[threadIdx.x >> 6] = sum;
  __syncthreads();
  if (threadIdx.x == 0) {
    int tot = red[0] + red[1] + red[2] + red[3];
    co[o] = -p->in_zp * tot;
    bias_out[o] = bias[o];
  }
}

// one block per frame n: quantize input frame, frame sum -> s[n]
__global__ __launch_bounds__(256) void quantx_kernel(
    const float* __restrict__ x, const Params* __restrict__ p,
    int8_t* __restrict__ qx, int* __restrict__ s) {
  const int n = blockIdx.x;
  const float is = p->in_scale;
  const float zpf = (float)p->in_zp;
  const float4 v = *((const float4*)(x + (size_t)n * D_DIM) + threadIdx.x);
  int8_t c0 = (int8_t)(int)rintf(v.x / is + zpf);
  int8_t c1 = (int8_t)(int)rintf(v.y / is + zpf);
  int8_t c2 = (int8_t)(int)rintf(v.z / is + zpf);
  int8_t c3 = (int8_t)(int)rintf(v.w / is + zpf);
  unsigned packed = (unsigned)(uint8_t)c0 | ((unsigned)(uint8_t)c1 << 8)
                  | ((unsigned)(uint8_t)c2 << 16) | ((unsigned)(uint8_t)c3 << 24);
  ((unsigned*)(qx + (size_t)n * D_DIM))[threadIdx.x] = packed;
  int sum = (int)c0 + (int)c1 + (int)c2 + (int)c3;
  __shared__ int red[4];
#pragma unroll
  for (int off = 32; off > 0; off >>= 1) sum += __shfl_xor(sum, off, 64);
  if ((threadIdx.x & 63) == 0) red[threadIdx.x >> 6] = sum;
  __syncthreads();
  if (threadIdx.x == 0) s[n] = red[0] + red[1] + red[2] + red[3];
}

// ct[t] = konst - w_zp * (s[t] + s[t+1] + s[t+2])
__global__ __launch_bounds__(256) void ct_kernel(const int* __restrict__ s,
                                                 const Params* __restrict__ p,
                                                 int* __restrict__ ct) {
  const int t = blockIdx.x * blockDim.x + threadIdx.x;
  if (t < T_DIM) ct[t] = p->konst - p->w_zp * (s[t] + s[t + 1] + s[t + 2]);
}

// int8 NT GEMM, 256x256 tile, BK=64, 8 waves, 2-phase-per-K-tile pipelined
// schedule with counted vmcnt + LDS XOR swizzle (T2+T3+T4+T5).
__global__ __launch_bounds__(512, 2) void gemm_kernel(
    const int8_t* __restrict__ qx, const int8_t* __restrict__ qw,
    const int* __restrict__ co, const int* __restrict__ ct,
    const float* __restrict__ bias, const Params* __restrict__ p,
    float* __restrict__ out) {
  __shared__ int8_t A_lds[2][256][64];   // [buf][tile row][k bytes], swizzled
  __shared__ int8_t B_lds[2][256][64];

  const int bid = blockIdx.x;
  const int tn = bid & 7;   // 8 n-tiles of 256 -> natural %8 spreads B panels across XCDs
  const int tm = bid >> 3;  // 64 m-tiles
  const int m0 = tm << 8, n0 = tn << 8;
  const int tid = threadIdx.x;
  const int lane = tid & 63, wave = tid >> 6;
  const int wm = wave >> 2, wn = wave & 3;  // 2 x 4 wave grid, per-wave 128x64 output
  const int lr = lane & 15, kg = lane >> 4;

  // staging geometry: one global_load_lds event = 512 threads x 16B = 8KB = 128 rows x 64B
  // thread tid covers LDS row (tid>>2), chunk (tid&3); source chunk pre-swizzled so that
  // linear LDS holds data with chunk ^= (row&3)  (read side applies the same XOR)
  const int st_r = tid >> 2;
  const int st_c = ((tid & 3) ^ (st_r & 3)) << 4;
  const int8_t* qx_base = qx + (size_t)(m0 + st_r) * D_DIM + st_c;
  const int8_t* qw_base = qw + (size_t)(n0 + st_r) * K_DIM + st_c;

  // fragment read column (swizzled): row&3 == lr&3 for all frag rows
  const int fc = ((kg ^ (lr & 3)) << 4);

  i32x4 acc[8][4] = {};

  auto stage_tile = [&](int buf, int kt) {
    const int ko = kt << 6;
    __builtin_amdgcn_global_load_lds((gbl_void*)(qx_base + ko),
        (lds_void*)(&A_lds[buf][0][0] + (wave << 10)), 16, 0, 0);
    __builtin_amdgcn_global_load_lds((gbl_void*)(qx_base + (size_t)128 * D_DIM + ko),
        (lds_void*)(&A_lds[buf][128][0] + (wave << 10)), 16, 0, 0);
    __builtin_amdgcn_global_load_lds((gbl_void*)(qw_base + ko),
        (lds_void*)(&B_lds[buf][0][0] + (wave << 10)), 16, 0, 0);
    __builtin_amdgcn_global_load_lds((gbl_void*)(qw_base + (size_t)128 * K_DIM + ko),
        (lds_void*)(&B_lds[buf][128][0] + (wave << 10)), 16, 0, 0);
  };

  // prologue: stage tiles 0 and 1; wait for tile 0 (4 loads of tile 1 stay in flight)
  stage_tile(0, 0);
  stage_tile(1, 1);
  asm volatile("s_waitcnt vmcnt(4)" ::: "memory");
  __builtin_amdgcn_s_barrier();

  for (int kt = 0; kt < NKT; ++kt) {
    const int buf = kt & 1;

    // ---- P0: all 12 ds_read_b128 frags; MFMA half (n=0,1) ----
    i32x4 af[8], bf[4];
#pragma unroll
    for (int m = 0; m < 8; ++m)
      af[m] = *(const i32x4*)&A_lds[buf][(wm << 7) + (m << 4) + lr][fc];
#pragma unroll
    for (int n = 0; n < 4; ++n)
      bf[n] = *(const i32x4*)&B_lds[buf][(wn << 6) + (n << 4) + lr][fc];
    __builtin_amdgcn_s_barrier();
    asm volatile("s_waitcnt lgkmcnt(0)" ::: "memory");
    __builtin_amdgcn_s_setprio(1);
#pragma unroll
    for (int m = 0; m < 8; ++m)
#pragma unroll
      for (int n = 0; n < 2; ++n)
        acc[m][n] = __builtin_amdgcn_mfma_i32_16x16x64_i8(af[m], bf[n], acc[m][n], 0, 0, 0);
    __builtin_amdgcn_s_setprio(0);
    __builtin_amdgcn_s_barrier();

    // ---- P1: stage tile kt+2 into this buffer (all reads drained above); MFMA half (n=2,3) ----
    if (kt + 2 < NKT) stage_tile(buf, kt + 2);
    __builtin_amdgcn_s_barrier();
    __builtin_amdgcn_s_setprio(1);
#pragma unroll
    for (int m = 0; m < 8; ++m)
#pragma unroll
      for (int n = 2; n < 4; ++n)
        acc[m][n] = __builtin_amdgcn_mfma_i32_16x16x64_i8(af[m], bf[n], acc[m][n], 0, 0, 0);
    __builtin_amdgcn_s_setprio(0);
    // counted vmcnt: ensure tile kt+1 (4 loads) complete; leave tile kt+2's 4 in flight
    if (kt < NKT - 2) {
      asm volatile("s_waitcnt vmcnt(4)" ::: "memory");
    } else if (kt == NKT - 2) {
      asm volatile("s_waitcnt vmcnt(0)" ::: "memory");
    }
    __builtin_amdgcn_s_barrier();
  }

  // epilogue: dequant + zero-point correction + bias
  const float cscale = p->cscale;
#pragma unroll
  for (int n = 0; n < 4; ++n) {
    const int o_ = n0 + (wn << 6) + (n << 4) + lr;
    const int cov = co[o_];
    const float bo = bias[o_];
#pragma unroll
    for (int m = 0; m < 8; ++m) {
      const int tbase = m0 + (wm << 7) + (m << 4) + (kg << 2);
#pragma unroll
      for (int r = 0; r < 4; ++r) {
        const int t_ = tbase + r;
        out[(size_t)t_ * O_DIM + o_] = (float)(acc[m][n][r] + cov + ct[t_]) * cscale + bo;
      }
    }
  }
}

extern "C" void kernel_launch(void* const* d_in, const int* in_sizes, int n_in,
                              void* d_out, int out_size, void* d_ws, size_t ws_size,
                              hipStream_t stream) {
  const float* x      = (const float*)d_in[0];
  const float* w      = (const float*)d_in[1];
  const float* bias   = (const float*)d_in[2];
  const float* in_min = (const float*)d_in[3];
  const float* in_max = (const float*)d_in[4];
  float* out = (float*)d_out;

  uint8_t* ws = (uint8_t*)d_ws;
  unsigned* mm = (unsigned*)(ws + WS_MM);
  Params*   prm = (Params*)(ws + WS_PARAMS);
  int*      co = (int*)(ws + WS_CO);
  int*      s  = (int*)(ws + WS_S);
  int*      ct = (int*)(ws + WS_CT);
  int8_t*   qw = (int8_t*)(ws + WS_QW);
  int8_t*   qx = (int8_t*)(ws + WS_QX);

  float* dq_out   = out + (size_t)T_DIM * O_DIM;            // output 1: dequant W
  float* bias_out = dq_out + (size_t)O_DIM * K_DIM;         // output 2: bias copy

  init_kernel<<<1, 1, 0, stream>>>(mm);
  wminmax_kernel<<<512, 256, 0, stream>>>((const float4*)w, mm, O_DIM * K_DIM / 4);
  params_kernel<<<1, 1, 0, stream>>>(mm, in_min, in_max, prm);
  quantw_kernel<<<O_DIM, 256, 0, stream>>>(w, bias, prm, qw, co, dq_out, bias_out);
  quantx_kernel<<<N_FRAMES, 256, 0, stream>>>(x, prm, qx, s);
  ct_kernel<<<T_DIM / 256, 256, 0, stream>>>(s, prm, ct);
  gemm_kernel<<<(T_DIM / 256) * (O_DIM / 256), 512, 0, stream>>>(qx, qw, co, ct, bias, prm, out);
}

// Round 3
// 223.850 us; speedup vs baseline: 1.0401x; 1.0401x over previous
//
#include <hip/hip_runtime.h>
#include <stdint.h>

typedef __attribute__((ext_vector_type(4))) int i32x4;

#define N_FRAMES 16386
#define D_DIM    1024
#define O_DIM    2048
#define L_CTX    3
#define K_DIM    3072   // D_DIM * L_CTX
#define T_DIM    16384  // N_FRAMES - L_CTX + 1
#define NKT      24     // K_DIM / 128  (128-byte K-tiles)

// workspace byte offsets
#define WS_MM     0u
#define WS_PARAMS 64u
#define WS_CO     256u
#define WS_S      16384u
#define WS_CT     98304u
#define WS_QW     262144u
#define WS_QX     8388608u

struct Params {
  float w_scale, in_scale, cscale;
  int   w_zp, in_zp, konst;
};

typedef __attribute__((address_space(3))) void       lds_void;
typedef const __attribute__((address_space(1))) void gbl_void;

__device__ __forceinline__ unsigned flip_f(float f) {
  unsigned u = __float_as_uint(f);
  return (u & 0x80000000u) ? ~u : (u | 0x80000000u);
}
__device__ __forceinline__ float unflip_f(unsigned v) {
  unsigned u = (v & 0x80000000u) ? (v ^ 0x80000000u) : ~v;
  return __uint_as_float(u);
}

__global__ void init_kernel(unsigned* mm) {
  mm[0] = 0xFFFFFFFFu;
  mm[1] = 0u;
}

__global__ __launch_bounds__(256) void wminmax_kernel(const float4* __restrict__ w,
                                                      unsigned* mm, int n4) {
  unsigned lmin = 0xFFFFFFFFu, lmax = 0u;
  for (int i = blockIdx.x * blockDim.x + threadIdx.x; i < n4; i += gridDim.x * blockDim.x) {
    float4 v = w[i];
    unsigned a = flip_f(v.x), b = flip_f(v.y), c = flip_f(v.z), d = flip_f(v.w);
    lmin = min(lmin, min(min(a, b), min(c, d)));
    lmax = max(lmax, max(max(a, b), max(c, d)));
  }
#pragma unroll
  for (int off = 32; off > 0; off >>= 1) {
    lmin = min(lmin, (unsigned)__shfl_xor((int)lmin, off, 64));
    lmax = max(lmax, (unsigned)__shfl_xor((int)lmax, off, 64));
  }
  if ((threadIdx.x & 63) == 0) {
    atomicMin(&mm[0], lmin);
    atomicMax(&mm[1], lmax);
  }
}

__global__ void params_kernel(const unsigned* __restrict__ mm,
                              const float* __restrict__ in_min,
                              const float* __restrict__ in_max,
                              Params* __restrict__ p) {
  float wmin = unflip_f(mm[0]);
  float wmax = unflip_f(mm[1]);
  float ws = (wmax - wmin) / 254.0f;
  float wz = -127.0f - wmin / ws;
  wz = fminf(fmaxf(wz, -127.0f), 127.0f);
  int wzp = (int)wz;
  float imin = *in_min, imax = *in_max;
  float is = (imax - imin) / 254.0f;
  float iz = -127.0f - imin / is;
  iz = fminf(fmaxf(iz, -127.0f), 127.0f);
  int izp = (int)iz;
  p->w_scale = ws; p->in_scale = is; p->cscale = is * ws;
  p->w_zp = wzp;   p->in_zp = izp;
  p->konst = K_DIM * wzp * izp;
}

__global__ __launch_bounds__(256) void quantw_kernel(
    const float* __restrict__ w, const float* __restrict__ bias,
    const Params* __restrict__ p, int8_t* __restrict__ qw,
    int* __restrict__ co, float* __restrict__ dq, float* __restrict__ bias_out) {
  const int o = blockIdx.x;
  const float ws = p->w_scale;
  const float zpf = (float)p->w_zp;
  const float* wrow = w + (size_t)o * K_DIM;
  float* dqrow = dq + (size_t)o * K_DIM;
  int8_t* qrow = qw + (size_t)o * K_DIM;
  int sum = 0;
#pragma unroll
  for (int pass = 0; pass < 3; ++pass) {
    const int k = (pass << 10) + (threadIdx.x << 2);
    float4 v = *(const float4*)(wrow + k);
    int8_t c0 = (int8_t)(int)rintf(v.x / ws + zpf);
    int8_t c1 = (int8_t)(int)rintf(v.y / ws + zpf);
    int8_t c2 = (int8_t)(int)rintf(v.z / ws + zpf);
    int8_t c3 = (int8_t)(int)rintf(v.w / ws + zpf);
    sum += (int)c0 + (int)c1 + (int)c2 + (int)c3;
    unsigned packed = (unsigned)(uint8_t)c0 | ((unsigned)(uint8_t)c1 << 8)
                    | ((unsigned)(uint8_t)c2 << 16) | ((unsigned)(uint8_t)c3 << 24);
    *(unsigned*)(qrow + k) = packed;
    float4 d;
    d.x = ((float)c0 - zpf) * ws;
    d.y = ((float)c1 - zpf) * ws;
    d.z = ((float)c2 - zpf) * ws;
    d.w = ((float)c3 - zpf) * ws;
    *(float4*)(dqrow + k) = d;
  }
  __shared__ int red[4];
#pragma unroll
  for (int off = 32; off > 0; off >>= 1) sum += __shfl_xor(sum, off, 64);
  if ((threadIdx.x & 63) == 0) red[threadIdx.x >> 6] = sum;
  __syncthreads();
  if (threadIdx.x == 0) {
    int tot = red[0] + red[1] + red[2] + red[3];
    co[o] = -p->in_zp * tot;
    bias_out[o] = bias[o];
  }
}

__global__ __launch_bounds__(256) void quantx_kernel(
    const float* __restrict__ x, const Params* __restrict__ p,
    int8_t* __restrict__ qx, int* __restrict__ s) {
  const int n = blockIdx.x;
  const float is = p->in_scale;
  const float zpf = (float)p->in_zp;
  const float4 v = *((const float4*)(x + (size_t)n * D_DIM) + threadIdx.x);
  int8_t c0 = (int8_t)(int)rintf(v.x / is + zpf);
  int8_t c1 = (int8_t)(int)rintf(v.y / is + zpf);
  int8_t c2 = (int8_t)(int)rintf(v.z / is + zpf);
  int8_t c3 = (int8_t)(int)rintf(v.w / is + zpf);
  unsigned packed = (unsigned)(uint8_t)c0 | ((unsigned)(uint8_t)c1 << 8)
                  | ((unsigned)(uint8_t)c2 << 16) | ((unsigned)(uint8_t)c3 << 24);
  ((unsigned*)(qx + (size_t)n * D_DIM))[threadIdx.x] = packed;
  int sum = (int)c0 + (int)c1 + (int)c2 + (int)c3;
  __shared__ int red[4];
#pragma unroll
  for (int off = 32; off > 0; off >>= 1) sum += __shfl_xor(sum, off, 64);
  if ((threadIdx.x & 63) == 0) red[threadIdx.x >> 6] = sum;
  __syncthreads();
  if (threadIdx.x == 0) s[n] = red[0] + red[1] + red[2] + red[3];
}

__global__ __launch_bounds__(256) void ct_kernel(const int* __restrict__ s,
                                                 const Params* __restrict__ p,
                                                 int* __restrict__ ct) {
  const int t = blockIdx.x * blockDim.x + threadIdx.x;
  if (t < T_DIM) ct[t] = p->konst - p->w_zp * (s[t] + s[t + 1] + s[t + 2]);
}

// int8 NT GEMM, 256x256 tile, 128B K-tiles, 8 waves, 4 phases per K-tile
// (m201-style): per-phase {ds_read subtile | stage half | bar | lgkm | 16 MFMA | bar},
// counted vmcnt(4) once per K-tile, chunk^row&7 LDS swizzle, setprio around MFMA.
__global__ __launch_bounds__(512, 2) void gemm_kernel(
    const int8_t* __restrict__ qx, const int8_t* __restrict__ qw,
    const int* __restrict__ co, const int* __restrict__ ct,
    const float* __restrict__ bias, const Params* __restrict__ p,
    float* __restrict__ out) {
  __shared__ int8_t A_lds[2][256 * 128];   // 32 KB per buf
  __shared__ int8_t B_lds[2][256 * 128];

  const int bid = blockIdx.x;
  const int tn = bid & 7;   // XCD-local n-tile: B panel L2-resident per XCD
  const int tm = bid >> 3;
  const int m0 = tm << 8, n0 = tn << 8;
  const int tid = threadIdx.x;
  const int lane = tid & 63, wave = tid >> 6;
  const int wm = wave >> 2, wn = wave & 3;   // 2x4 wave grid, per-wave 128x64
  const int lr = lane & 15, kg = lane >> 4;
  const int lr7 = lane & 7;

  // staging: one gload event/wave = 64 lanes x 16B = 1KB = 8 rows x 128B.
  // thread t covers row t>>3, lds chunk t&7; global source chunk pre-swizzled
  // with ^(row&7) so linear LDS dest holds swizzled layout (#21).
  const int st_row = tid >> 3;                       // 0..63
  const int st_sc  = ((tid & 7) ^ (st_row & 7)) << 4;
  const int8_t* qxa = qx + (size_t)(m0 + st_row) * D_DIM + st_sc;
  const int8_t* qwb = qw + (size_t)(n0 + st_row) * K_DIM + st_sc;

  // fragment read: row = <frag row> + lr, phys chunk = (ks*4+kg) ^ (row&7), row&7==lr7
  const int c0 = (kg ^ lr7) << 4;                    // ks=0 chunk byte offset; ks=1: c0^64
  const int arow = ((wm << 7) + lr) << 7;            // A row base byte (row*128)
  const int brow = ((wn << 6) + lr) << 7;

  i32x4 a0[4][2], a1[4][2], b0[2][2], b1[2][2];
  i32x4 acc[8][4] = {};

  auto stageA = [&](int buf, int kt) {
    const int8_t* s = qxa + (kt << 7);
#pragma unroll
    for (int j = 0; j < 4; ++j)
      __builtin_amdgcn_global_load_lds((gbl_void*)(s + (size_t)(j << 6) * D_DIM),
          (lds_void*)(&A_lds[buf][(j << 13) + (wave << 10)]), 16, 0, 0);
  };
  auto stageB = [&](int buf, int kt) {
    const int8_t* s = qwb + (kt << 7);
#pragma unroll
    for (int j = 0; j < 4; ++j)
      __builtin_amdgcn_global_load_lds((gbl_void*)(s + (size_t)(j << 6) * K_DIM),
          (lds_void*)(&B_lds[buf][(j << 13) + (wave << 10)]), 16, 0, 0);
  };

  // prologue: tiles 0,1 staged; wait tile 0 (tile 1's 8 loads stay in flight)
  stageA(0, 0); stageB(0, 0);
  stageA(1, 1); stageB(1, 1);
  asm volatile("s_waitcnt vmcnt(8)" ::: "memory");
  __builtin_amdgcn_s_barrier();

  // initial register frags: A0(t0), B0(t0)
#pragma unroll
  for (int i = 0; i < 4; ++i)
#pragma unroll
    for (int ks = 0; ks < 2; ++ks)
      a0[i][ks] = *(const i32x4*)&A_lds[0][arow + (i << 11) + (c0 ^ (ks << 6))];
#pragma unroll
  for (int j = 0; j < 2; ++j)
#pragma unroll
    for (int ks = 0; ks < 2; ++ks)
      b0[j][ks] = *(const i32x4*)&B_lds[0][brow + (j << 11) + (c0 ^ (ks << 6))];

  for (int kt = 0; kt < NKT; ++kt) {
    const int buf = kt & 1, nxt = buf ^ 1;

    // ---- P0: ds_read A1(cur); MFMA A0xB0 (quadrant m0-3, n0-1) ----
#pragma unroll
    for (int i = 0; i < 4; ++i)
#pragma unroll
      for (int ks = 0; ks < 2; ++ks)
        a1[i][ks] = *(const i32x4*)&A_lds[buf][arow + ((i + 4) << 11) + (c0 ^ (ks << 6))];
    __builtin_amdgcn_s_barrier();
    asm volatile("s_waitcnt lgkmcnt(0)" ::: "memory");
    __builtin_amdgcn_sched_barrier(0);
    __builtin_amdgcn_s_setprio(1);
#pragma unroll
    for (int i = 0; i < 4; ++i)
#pragma unroll
      for (int n = 0; n < 2; ++n)
#pragma unroll
        for (int ks = 0; ks < 2; ++ks)
          acc[i][n] = __builtin_amdgcn_mfma_i32_16x16x64_i8(a0[i][ks], b0[n][ks], acc[i][n], 0, 0, 0);
    __builtin_amdgcn_s_setprio(0);
    __builtin_amdgcn_s_barrier();

    // ---- P1: ds_read B1(cur); stage A(kt+2); MFMA A1xB0; vmcnt gate ----
#pragma unroll
    for (int j = 0; j < 2; ++j)
#pragma unroll
      for (int ks = 0; ks < 2; ++ks)
        b1[j][ks] = *(const i32x4*)&B_lds[buf][brow + ((j + 2) << 11) + (c0 ^ (ks << 6))];
    if (kt + 2 < NKT) stageA(buf, kt + 2);
    __builtin_amdgcn_s_barrier();
    asm volatile("s_waitcnt lgkmcnt(0)" ::: "memory");
    __builtin_amdgcn_sched_barrier(0);
    __builtin_amdgcn_s_setprio(1);
#pragma unroll
    for (int i = 0; i < 4; ++i)
#pragma unroll
      for (int n = 0; n < 2; ++n)
#pragma unroll
        for (int ks = 0; ks < 2; ++ks)
          acc[i + 4][n] = __builtin_amdgcn_mfma_i32_16x16x64_i8(a1[i][ks], b0[n][ks], acc[i + 4][n], 0, 0, 0);
    __builtin_amdgcn_s_setprio(0);
    if (kt + 2 < NKT) {
      asm volatile("s_waitcnt vmcnt(4)" ::: "memory");   // tile kt+1 landed; kt+2's A in flight
    } else if (kt + 1 < NKT) {
      asm volatile("s_waitcnt vmcnt(0)" ::: "memory");
    }
    __builtin_amdgcn_s_barrier();

    // ---- P2: ds_read B0(next) [gated]; stage B(kt+2); MFMA A0xB1 ----
    if (kt + 1 < NKT) {
#pragma unroll
      for (int j = 0; j < 2; ++j)
#pragma unroll
        for (int ks = 0; ks < 2; ++ks)
          b0[j][ks] = *(const i32x4*)&B_lds[nxt][brow + (j << 11) + (c0 ^ (ks << 6))];
    }
    if (kt + 2 < NKT) stageB(buf, kt + 2);
    __builtin_amdgcn_s_barrier();
    asm volatile("s_waitcnt lgkmcnt(0)" ::: "memory");
    __builtin_amdgcn_sched_barrier(0);
    __builtin_amdgcn_s_setprio(1);
#pragma unroll
    for (int i = 0; i < 4; ++i)
#pragma unroll
      for (int n = 0; n < 2; ++n)
#pragma unroll
        for (int ks = 0; ks < 2; ++ks)
          acc[i][n + 2] = __builtin_amdgcn_mfma_i32_16x16x64_i8(a0[i][ks], b1[n][ks], acc[i][n + 2], 0, 0, 0);
    __builtin_amdgcn_s_setprio(0);
    __builtin_amdgcn_s_barrier();

    // ---- P3: ds_read A0(next); MFMA A1xB1 ----
    if (kt + 1 < NKT) {
#pragma unroll
      for (int i = 0; i < 4; ++i)
#pragma unroll
        for (int ks = 0; ks < 2; ++ks)
          a0[i][ks] = *(const i32x4*)&A_lds[nxt][arow + (i << 11) + (c0 ^ (ks << 6))];
    }
    __builtin_amdgcn_s_barrier();
    asm volatile("s_waitcnt lgkmcnt(0)" ::: "memory");
    __builtin_amdgcn_sched_barrier(0);
    __builtin_amdgcn_s_setprio(1);
#pragma unroll
    for (int i = 0; i < 4; ++i)
#pragma unroll
      for (int n = 0; n < 2; ++n)
#pragma unroll
        for (int ks = 0; ks < 2; ++ks)
          acc[i + 4][n + 2] = __builtin_amdgcn_mfma_i32_16x16x64_i8(a1[i][ks], b1[n][ks], acc[i + 4][n + 2], 0, 0, 0);
    __builtin_amdgcn_s_setprio(0);
    __builtin_amdgcn_s_barrier();
  }

  // epilogue: dequant + zero-point correction + bias
  const float cscale = p->cscale;
#pragma unroll
  for (int n = 0; n < 4; ++n) {
    const int o_ = n0 + (wn << 6) + (n << 4) + lr;
    const int cov = co[o_];
    const float bo = bias[o_];
#pragma unroll
    for (int m = 0; m < 8; ++m) {
      const int tbase = m0 + (wm << 7) + (m << 4) + (kg << 2);
#pragma unroll
      for (int r = 0; r < 4; ++r) {
        const int t_ = tbase + r;
        out[(size_t)t_ * O_DIM + o_] = (float)(acc[m][n][r] + cov + ct[t_]) * cscale + bo;
      }
    }
  }
}

extern "C" void kernel_launch(void* const* d_in, const int* in_sizes, int n_in,
                              void* d_out, int out_size, void* d_ws, size_t ws_size,
                              hipStream_t stream) {
  const float* x      = (const float*)d_in[0];
  const float* w      = (const float*)d_in[1];
  const float* bias   = (const float*)d_in[2];
  const float* in_min = (const float*)d_in[3];
  const float* in_max = (const float*)d_in[4];
  float* out = (float*)d_out;

  uint8_t* ws = (uint8_t*)d_ws;
  unsigned* mm = (unsigned*)(ws + WS_MM);
  Params*   prm = (Params*)(ws + WS_PARAMS);
  int*      co = (int*)(ws + WS_CO);
  int*      s  = (int*)(ws + WS_S);
  int*      ct = (int*)(ws + WS_CT);
  int8_t*   qw = (int8_t*)(ws + WS_QW);
  int8_t*   qx = (int8_t*)(ws + WS_QX);

  float* dq_out   = out + (size_t)T_DIM * O_DIM;
  float* bias_out = dq_out + (size_t)O_DIM * K_DIM;

  init_kernel<<<1, 1, 0, stream>>>(mm);
  wminmax_kernel<<<512, 256, 0, stream>>>((const float4*)w, mm, O_DIM * K_DIM / 4);
  params_kernel<<<1, 1, 0, stream>>>(mm, in_min, in_max, prm);
  quantw_kernel<<<O_DIM, 256, 0, stream>>>(w, bias, prm, qw, co, dq_out, bias_out);
  quantx_kernel<<<N_FRAMES, 256, 0, stream>>>(x, prm, qx, s);
  ct_kernel<<<T_DIM / 256, 256, 0, stream>>>(s, prm, ct);
  gemm_kernel<<<(T_DIM / 256) * (O_DIM / 256), 512, 0, stream>>>(qx, qw, co, ct, bias, prm, out);
}

// Round 4
// 202.324 us; speedup vs baseline: 1.1508x; 1.1064x over previous
//
#include <hip/hip_runtime.h>
#include <stdint.h>

typedef __attribute__((ext_vector_type(4))) int i32x4;

#define N_FRAMES 16386
#define D_DIM    1024
#define O_DIM    2048
#define L_CTX    3
#define K_DIM    3072   // D_DIM * L_CTX
#define T_DIM    16384  // N_FRAMES - L_CTX + 1
#define NKT      24     // K_DIM / 128  (128-byte K-tiles)

// workspace byte offsets
#define WS_MM     0u
#define WS_PARAMS 64u
#define WS_CO     256u
#define WS_S      16384u
#define WS_CT     98304u
#define WS_QW     262144u
#define WS_QX     8388608u

struct Params {
  float w_scale, in_scale, cscale;
  int   w_zp, in_zp, konst;
};

typedef __attribute__((address_space(3))) void       lds_void;
typedef const __attribute__((address_space(1))) void gbl_void;

__device__ __forceinline__ unsigned flip_f(float f) {
  unsigned u = __float_as_uint(f);
  return (u & 0x80000000u) ? ~u : (u | 0x80000000u);
}
__device__ __forceinline__ float unflip_f(unsigned v) {
  unsigned u = (v & 0x80000000u) ? (v ^ 0x80000000u) : ~v;
  return __uint_as_float(u);
}

__global__ void init_kernel(unsigned* mm) {
  mm[0] = 0xFFFFFFFFu;
  mm[1] = 0u;
}

__global__ __launch_bounds__(256) void wminmax_kernel(const float4* __restrict__ w,
                                                      unsigned* mm, int n4) {
  unsigned lmin = 0xFFFFFFFFu, lmax = 0u;
  for (int i = blockIdx.x * blockDim.x + threadIdx.x; i < n4; i += gridDim.x * blockDim.x) {
    float4 v = w[i];
    unsigned a = flip_f(v.x), b = flip_f(v.y), c = flip_f(v.z), d = flip_f(v.w);
    lmin = min(lmin, min(min(a, b), min(c, d)));
    lmax = max(lmax, max(max(a, b), max(c, d)));
  }
#pragma unroll
  for (int off = 32; off > 0; off >>= 1) {
    lmin = min(lmin, (unsigned)__shfl_xor((int)lmin, off, 64));
    lmax = max(lmax, (unsigned)__shfl_xor((int)lmax, off, 64));
  }
  if ((threadIdx.x & 63) == 0) {
    atomicMin(&mm[0], lmin);
    atomicMax(&mm[1], lmax);
  }
}

__global__ void params_kernel(const unsigned* __restrict__ mm,
                              const float* __restrict__ in_min,
                              const float* __restrict__ in_max,
                              Params* __restrict__ p) {
  float wmin = unflip_f(mm[0]);
  float wmax = unflip_f(mm[1]);
  float ws = (wmax - wmin) / 254.0f;
  float wz = -127.0f - wmin / ws;
  wz = fminf(fmaxf(wz, -127.0f), 127.0f);
  int wzp = (int)wz;
  float imin = *in_min, imax = *in_max;
  float is = (imax - imin) / 254.0f;
  float iz = -127.0f - imin / is;
  iz = fminf(fmaxf(iz, -127.0f), 127.0f);
  int izp = (int)iz;
  p->w_scale = ws; p->in_scale = is; p->cscale = is * ws;
  p->w_zp = wzp;   p->in_zp = izp;
  p->konst = K_DIM * wzp * izp;
}

__global__ __launch_bounds__(256) void quantw_kernel(
    const float* __restrict__ w, const float* __restrict__ bias,
    const Params* __restrict__ p, int8_t* __restrict__ qw,
    int* __restrict__ co, float* __restrict__ dq, float* __restrict__ bias_out) {
  const int o = blockIdx.x;
  const float ws = p->w_scale;
  const float zpf = (float)p->w_zp;
  const float* wrow = w + (size_t)o * K_DIM;
  float* dqrow = dq + (size_t)o * K_DIM;
  int8_t* qrow = qw + (size_t)o * K_DIM;
  int sum = 0;
#pragma unroll
  for (int pass = 0; pass < 3; ++pass) {
    const int k = (pass << 10) + (threadIdx.x << 2);
    float4 v = *(const float4*)(wrow + k);
    int8_t c0 = (int8_t)(int)rintf(v.x / ws + zpf);
    int8_t c1 = (int8_t)(int)rintf(v.y / ws + zpf);
    int8_t c2 = (int8_t)(int)rintf(v.z / ws + zpf);
    int8_t c3 = (int8_t)(int)rintf(v.w / ws + zpf);
    sum += (int)c0 + (int)c1 + (int)c2 + (int)c3;
    unsigned packed = (unsigned)(uint8_t)c0 | ((unsigned)(uint8_t)c1 << 8)
                    | ((unsigned)(uint8_t)c2 << 16) | ((unsigned)(uint8_t)c3 << 24);
    *(unsigned*)(qrow + k) = packed;
    float4 d;
    d.x = ((float)c0 - zpf) * ws;
    d.y = ((float)c1 - zpf) * ws;
    d.z = ((float)c2 - zpf) * ws;
    d.w = ((float)c3 - zpf) * ws;
    *(float4*)(dqrow + k) = d;
  }
  __shared__ int red[4];
#pragma unroll
  for (int off = 32; off > 0; off >>= 1) sum += __shfl_xor(sum, off, 64);
  if ((threadIdx.x & 63) == 0) red[threadIdx.x >> 6] = sum;
  __syncthreads();
  if (threadIdx.x == 0) {
    int tot = red[0] + red[1] + red[2] + red[3];
    co[o] = -p->in_zp * tot;
    bias_out[o] = bias[o];
  }
}

__global__ __launch_bounds__(256) void quantx_kernel(
    const float* __restrict__ x, const Params* __restrict__ p,
    int8_t* __restrict__ qx, int* __restrict__ s) {
  const int n = blockIdx.x;
  const float is = p->in_scale;
  const float zpf = (float)p->in_zp;
  const float4 v = *((const float4*)(x + (size_t)n * D_DIM) + threadIdx.x);
  int8_t c0 = (int8_t)(int)rintf(v.x / is + zpf);
  int8_t c1 = (int8_t)(int)rintf(v.y / is + zpf);
  int8_t c2 = (int8_t)(int)rintf(v.z / is + zpf);
  int8_t c3 = (int8_t)(int)rintf(v.w / is + zpf);
  unsigned packed = (unsigned)(uint8_t)c0 | ((unsigned)(uint8_t)c1 << 8)
                  | ((unsigned)(uint8_t)c2 << 16) | ((unsigned)(uint8_t)c3 << 24);
  ((unsigned*)(qx + (size_t)n * D_DIM))[threadIdx.x] = packed;
  int sum = (int)c0 + (int)c1 + (int)c2 + (int)c3;
  __shared__ int red[4];
#pragma unroll
  for (int off = 32; off > 0; off >>= 1) sum += __shfl_xor(sum, off, 64);
  if ((threadIdx.x & 63) == 0) red[threadIdx.x >> 6] = sum;
  __syncthreads();
  if (threadIdx.x == 0) s[n] = red[0] + red[1] + red[2] + red[3];
}

__global__ __launch_bounds__(256) void ct_kernel(const int* __restrict__ s,
                                                 const Params* __restrict__ p,
                                                 int* __restrict__ ct) {
  const int t = blockIdx.x * blockDim.x + threadIdx.x;
  if (t < T_DIM) ct[t] = p->konst - p->w_zp * (s[t] + s[t + 1] + s[t + 2]);
}

// int8 NT GEMM, 256x256 tile, 128B K-tiles, 8 waves.
// 2 phases per K-tile: {12 ds_read (next ks-half) | bar | lgkmcnt(12) counted |
// [stage 8 gloads, P1 only] | setprio | 32 MFMA | setprio | [vmcnt(0), P0 only,
// 1 K-tile slack] | bar}. No sched_barrier, no full lgkm drains.
__global__ __launch_bounds__(512, 2) void gemm_kernel(
    const int8_t* __restrict__ qx, const int8_t* __restrict__ qw,
    const int* __restrict__ co, const int* __restrict__ ct,
    const float* __restrict__ bias, const Params* __restrict__ p,
    float* __restrict__ out) {
  __shared__ int8_t A_lds[2][256 * 128];   // 32 KB per buf
  __shared__ int8_t B_lds[2][256 * 128];

  const int bid = blockIdx.x;
  const int tn = bid & 7;   // XCD-local n-tile: B panel L2-resident per XCD
  const int tm = bid >> 3;
  const int m0 = tm << 8, n0 = tn << 8;
  const int tid = threadIdx.x;
  const int lane = tid & 63, wave = tid >> 6;
  const int wm = wave >> 2, wn = wave & 3;   // 2x4 wave grid, per-wave 128x64
  const int lr = lane & 15, kg = lane >> 4;
  const int lr7 = lane & 7;

  // staging: thread t covers row t>>3, lds chunk t&7; source chunk pre-swizzled
  // with ^(row&7) so linear LDS dest holds swizzled layout.
  const int st_row = tid >> 3;
  const int st_sc  = ((tid & 7) ^ (st_row & 7)) << 4;
  const int8_t* qxa = qx + (size_t)(m0 + st_row) * D_DIM + st_sc;
  const int8_t* qwb = qw + (size_t)(n0 + st_row) * K_DIM + st_sc;

  // fragment read: phys chunk = ((ks<<2)|kg) ^ (row&7); row&7 == lr7
  const int c0 = (kg ^ lr7) << 4;            // ks=0; ks=1 -> c0 ^ 64
  const int arow = ((wm << 7) + lr) << 7;    // A row base byte
  const int brow = ((wn << 6) + lr) << 7;

  i32x4 a[8][2], b[4][2];
  i32x4 acc[8][4] = {};

  auto stageA = [&](int buf, int kt) {
    const int8_t* s = qxa + (kt << 7);
#pragma unroll
    for (int j = 0; j < 4; ++j)
      __builtin_amdgcn_global_load_lds((gbl_void*)(s + (size_t)(j << 6) * D_DIM),
          (lds_void*)(&A_lds[buf][(j << 13) + (wave << 10)]), 16, 0, 0);
  };
  auto stageB = [&](int buf, int kt) {
    const int8_t* s = qwb + (kt << 7);
#pragma unroll
    for (int j = 0; j < 4; ++j)
      __builtin_amdgcn_global_load_lds((gbl_void*)(s + (size_t)(j << 6) * K_DIM),
          (lds_void*)(&B_lds[buf][(j << 13) + (wave << 10)]), 16, 0, 0);
  };
  // 12 ds_read_b128 of one ks-half of tile's fragments from LDS buffer bf
  auto read_half = [&](int bf, int ks) {
#pragma unroll
    for (int m = 0; m < 8; ++m)
      a[m][ks] = *(const i32x4*)&A_lds[bf][arow + (m << 11) + (c0 ^ (ks << 6))];
#pragma unroll
    for (int n = 0; n < 4; ++n)
      b[n][ks] = *(const i32x4*)&B_lds[bf][brow + (n << 11) + (c0 ^ (ks << 6))];
  };

  // prologue: stage tiles 0,1; wait tile 0 (tile 1's 8 loads stay in flight);
  // read ks=0 half of tile 0.
  stageA(0, 0); stageB(0, 0);
  stageA(1, 1); stageB(1, 1);
  asm volatile("s_waitcnt vmcnt(8)" ::: "memory");
  __builtin_amdgcn_s_barrier();
  read_half(0, 0);

  for (int kt = 0; kt < NKT; ++kt) {
    const int buf = kt & 1, nxt = buf ^ 1;

    // ---- P0: ds_read ks=1 half (tile kt, buf); MFMA ks=0 ----
    read_half(buf, 1);
    __builtin_amdgcn_s_barrier();
    asm volatile("s_waitcnt lgkmcnt(12)" ::: "memory");  // prev 12 reads done; ours fly
    __builtin_amdgcn_s_setprio(1);
#pragma unroll
    for (int m = 0; m < 8; ++m)
#pragma unroll
      for (int n = 0; n < 4; ++n)
        acc[m][n] = __builtin_amdgcn_mfma_i32_16x16x64_i8(a[m][0], b[n][0], acc[m][n], 0, 0, 0);
    __builtin_amdgcn_s_setprio(0);
    // drain stage(kt+1) (issued a full K-tile ago -> landed; near-free wait)
    asm volatile("s_waitcnt vmcnt(0)" ::: "memory");
    __builtin_amdgcn_s_barrier();

    // ---- P1: ds_read ks=0 half (tile kt+1, nxt); stage kt+2 -> buf; MFMA ks=1 ----
    if (kt + 1 < NKT) read_half(nxt, 0);
    __builtin_amdgcn_s_barrier();
    if (kt + 1 < NKT) {
      asm volatile("s_waitcnt lgkmcnt(12)" ::: "memory");  // P0's 12 done; ours fly
    } else {
      asm volatile("s_waitcnt lgkmcnt(0)" ::: "memory");   // last iter: drain P0's reads
    }
    if (kt + 2 < NKT) { stageA(buf, kt + 2); stageB(buf, kt + 2); }  // buf reads drained above
    __builtin_amdgcn_s_setprio(1);
#pragma unroll
    for (int m = 0; m < 8; ++m)
#pragma unroll
      for (int n = 0; n < 4; ++n)
        acc[m][n] = __builtin_amdgcn_mfma_i32_16x16x64_i8(a[m][1], b[n][1], acc[m][n], 0, 0, 0);
    __builtin_amdgcn_s_setprio(0);
    __builtin_amdgcn_s_barrier();
  }

  // epilogue: dequant + zero-point correction + bias
  const float cscale = p->cscale;
  int   cov[4];
  float bov[4];
#pragma unroll
  for (int n = 0; n < 4; ++n) {
    const int o_ = n0 + (wn << 6) + (n << 4) + lr;
    cov[n] = co[o_];
    bov[n] = bias[o_];
  }
#pragma unroll
  for (int m = 0; m < 8; ++m) {
    const int tbase = m0 + (wm << 7) + (m << 4) + (kg << 2);
    int ctv[4];
#pragma unroll
    for (int r = 0; r < 4; ++r) ctv[r] = ct[tbase + r];
#pragma unroll
    for (int n = 0; n < 4; ++n) {
      const int o_ = n0 + (wn << 6) + (n << 4) + lr;
#pragma unroll
      for (int r = 0; r < 4; ++r) {
        out[(size_t)(tbase + r) * O_DIM + o_] =
            (float)(acc[m][n][r] + cov[n] + ctv[r]) * cscale + bov[n];
      }
    }
  }
}

extern "C" void kernel_launch(void* const* d_in, const int* in_sizes, int n_in,
                              void* d_out, int out_size, void* d_ws, size_t ws_size,
                              hipStream_t stream) {
  const float* x      = (const float*)d_in[0];
  const float* w      = (const float*)d_in[1];
  const float* bias   = (const float*)d_in[2];
  const float* in_min = (const float*)d_in[3];
  const float* in_max = (const float*)d_in[4];
  float* out = (float*)d_out;

  uint8_t* ws = (uint8_t*)d_ws;
  unsigned* mm = (unsigned*)(ws + WS_MM);
  Params*   prm = (Params*)(ws + WS_PARAMS);
  int*      co = (int*)(ws + WS_CO);
  int*      s  = (int*)(ws + WS_S);
  int*      ct = (int*)(ws + WS_CT);
  int8_t*   qw = (int8_t*)(ws + WS_QW);
  int8_t*   qx = (int8_t*)(ws + WS_QX);

  float* dq_out   = out + (size_t)T_DIM * O_DIM;
  float* bias_out = dq_out + (size_t)O_DIM * K_DIM;

  init_kernel<<<1, 1, 0, stream>>>(mm);
  wminmax_kernel<<<512, 256, 0, stream>>>((const float4*)w, mm, O_DIM * K_DIM / 4);
  params_kernel<<<1, 1, 0, stream>>>(mm, in_min, in_max, prm);
  quantw_kernel<<<O_DIM, 256, 0, stream>>>(w, bias, prm, qw, co, dq_out, bias_out);
  quantx_kernel<<<N_FRAMES, 256, 0, stream>>>(x, prm, qx, s);
  ct_kernel<<<T_DIM / 256, 256, 0, stream>>>(s, prm, ct);
  gemm_kernel<<<(T_DIM / 256) * (O_DIM / 256), 512, 0, stream>>>(qx, qw, co, ct, bias, prm, out);
}